// Round 11
// baseline (429.740 us; speedup 1.0000x reference)
//
#include <hip/hip_runtime.h>
#include <hip/hip_bf16.h>

#define N_NODES 50000
#define N_EDGES 600000
#define F 128
#define R 2
#define NLAYER 4
#define NSEG (N_NODES * R)  /* 100000 */
#define SEGP (NSEG / 8)     /* 12500 segments per XCD group */
#define NSCB 98             /* scan blocks: ceil(100000/1024) */
#define NB 384              /* gemm out cols: 256 y + 128 z */
#define STATS_STRIDE 2048   /* 8 copies x 256 floats per layer */
#define AGGB 6250           /* aggregate blocks: 512 thr -> 50000 waves */
#define PCAP 76800          /* per-XCD-group bucket capacity (7 sigma) */
#define PARTB 512           /* partition blocks */
#define BN_EPS 1e-5f
#define BETA 1e-4f

typedef __hip_bfloat16 bf16;
typedef __attribute__((ext_vector_type(8))) short short8;  // 8 bf16 (4 VGPRs)
typedef __attribute__((ext_vector_type(4))) short short4x; // 4 bf16 (2 VGPRs)
typedef __attribute__((ext_vector_type(4))) float floatx4; // 4 fp32 acc

__device__ __forceinline__ float b2f(short s) {
    union { unsigned u; float f; } c;
    c.u = ((unsigned)(unsigned short)s) << 16;
    return c.f;
}

// ---------------- weight transpose + f32->bf16: Bt[l][j][d] = W[l][d][j] ----------------
// cols j: [0,128)=W_rel[0], [128,256)=W_rel[1], [256,384)=W_root
__global__ void k_wt(const float* __restrict__ W0_rel, const float* __restrict__ W0_root,
                     const float* __restrict__ Ws_rel, const float* __restrict__ Ws_root,
                     bf16* __restrict__ Bt) {
    int idx = blockIdx.x * 256 + threadIdx.x;
    if (idx >= NLAYER * NB * F) return;
    int l = idx / (NB * F);
    int rem = idx % (NB * F);
    int j = rem / F, d = rem % F;
    float v;
    if (j < 256) {
        int r = j >> 7, c = j & 127;
        v = (l == 0) ? W0_rel[(r * F + d) * F + c]
                     : Ws_rel[((size_t)((l - 1) * R + r) * F + d) * F + c];
    } else {
        int c = j - 256;
        v = (l == 0) ? W0_root[d * F + c]
                     : Ws_root[((size_t)(l - 1) * F + d) * F + c];
    }
    Bt[idx] = __float2bfloat16(v);
}

// ---------------- one-pass 8-bucket edge partition ----------------
// Buckets edges by XCD group g = seg/SEGP into contiguous regions so the
// count/fill passes scan ONLY their own 75K-edge bucket instead of
// ownership-filtering all 600K edges 8x. Bucket sizes are fixed constants
// of the (fixed) graph; PCAP = 76800 is 7 sigma above Binomial(600K,1/8).
__global__ void k_part(const int* __restrict__ dst, const int* __restrict__ et,
                       const int* __restrict__ src,
                       int* __restrict__ eseg, int* __restrict__ esrcb,
                       int* __restrict__ bcnt) {
    __shared__ int hist[8], base[8], cur[8];
    int t = threadIdx.x;
    if (t < 8) hist[t] = 0;
    __syncthreads();
    int per = (N_EDGES + PARTB - 1) / PARTB;   // 1172
    int e0 = blockIdx.x * per;
    int e1 = e0 + per; if (e1 > N_EDGES) e1 = N_EDGES;
    for (int e = e0 + t; e < e1; e += 256) {
        int s = dst[e] * R + et[e];
        atomicAdd(&hist[s / SEGP], 1);
    }
    __syncthreads();
    if (t < 8) {
        base[t] = atomicAdd(&bcnt[t], hist[t]);
        cur[t] = 0;
    }
    __syncthreads();
    for (int e = e0 + t; e < e1; e += 256) {
        int s = dst[e] * R + et[e];
        int g = s / SEGP;
        int idx = g * PCAP + base[g] + atomicAdd(&cur[g], 1);
        eseg[idx] = s;
        esrcb[idx] = src[e];
    }
}

// ---------------- segment counts (XCD-partitioned, bucket scan) ----------------
// blocks with blockIdx&7==g scan only bucket g -> cnt lines stay in ONE
// XCD's L2 AND no wasted ownership predicates.
__global__ void k_count(const int* __restrict__ eseg, const int* __restrict__ bcnt,
                        int* __restrict__ cnt) {
    int g = blockIdx.x & 7;
    int n = bcnt[g];
    const int* p = eseg + (size_t)g * PCAP;
    for (int i = (blockIdx.x >> 3) * 256 + threadIdx.x; i < n; i += 65536)
        atomicAdd(&cnt[p[i]], 1);
}

// ---------------- multi-block exclusive scan of cnt ----------------
__global__ void k_scan1(const int* __restrict__ cnt, int* __restrict__ off,
                        int* __restrict__ bsum) {
    int t = threadIdx.x;
    int g = blockIdx.x * 1024 + t;
    int v = (g < NSEG) ? cnt[g] : 0;
    int lane = t & 63;
    int wv = t >> 6;
    int x = v;
    for (int d = 1; d < 64; d <<= 1) {
        int y = __shfl_up(x, d, 64);
        if (lane >= d) x += y;
    }
    __shared__ int wtot[16];
    if (lane == 63) wtot[wv] = x;
    __syncthreads();
    if (t < 16) {
        int s = wtot[t];
        for (int d = 1; d < 16; d <<= 1) {
            int y = __shfl_up(s, d, 64);
            if (t >= d) s += y;
        }
        wtot[t] = s;
    }
    __syncthreads();
    int wpre = (wv == 0) ? 0 : wtot[wv - 1];
    int incl = x + wpre;
    if (g < NSEG) off[g] = incl - v;  // exclusive within block
    if (t == 1023) bsum[blockIdx.x] = incl;  // raw block total
}

// scan2 merged in: each block's thread 0 sums preceding block totals (L2-hot).
__global__ void k_scan3(int* __restrict__ off, const int* __restrict__ bsum) {
    __shared__ int pre;
    if (threadIdx.x == 0) {
        int p = 0;
        for (int b = 0; b < blockIdx.x; b++) p += bsum[b];
        pre = p;
    }
    __syncthreads();
    int g = blockIdx.x * 1024 + threadIdx.x;
    if (g < NSEG) off[g] += pre;
}

// ---------------- fill segment-sorted src list (XCD-partitioned, bucket scan) ----------------
__global__ void k_fill(const int* __restrict__ eseg, const int* __restrict__ esrcb,
                       const int* __restrict__ bcnt, const int* __restrict__ off,
                       int* __restrict__ fill, int* __restrict__ esrc) {
    int g = blockIdx.x & 7;
    int n = bcnt[g];
    const int* ps = eseg + (size_t)g * PCAP;
    const int* pr = esrcb + (size_t)g * PCAP;
    for (int i = (blockIdx.x >> 3) * 256 + threadIdx.x; i < n; i += 65536) {
        int s = ps[i];
        int idx = off[s] + atomicAdd(&fill[s], 1);
        esrc[idx] = pr[i];
    }
}

// ---------------- BN column stats for x (layer 0 only) ----------------
// Writes copy 0 of the 8-way stats buffer; copies 1-7 stay zero (memset).
__global__ void k_bnstats(const float* __restrict__ h, float* __restrict__ gs) {
    int c = threadIdx.x & 127;
    int rl = threadIdx.x >> 7;
    float s = 0.f, q = 0.f;
    for (int r = blockIdx.x * 2 + rl; r < N_NODES; r += gridDim.x * 2) {
        float v = h[(size_t)r * F + c];
        s += v; q += v * v;
    }
    __shared__ float ls[256], lq[256];
    ls[threadIdx.x] = s; lq[threadIdx.x] = q;
    __syncthreads();
    if (rl == 0) {
        atomicAdd(&gs[c], ls[c] + ls[c + 128]);
        atomicAdd(&gs[128 + c], lq[c] + lq[c + 128]);
    }
}

// ---------------- fused BN-apply + GEMM: [y|z] = bn(h) @ [Wr0|Wr1|Wroot] ----------------
// Block = 64-row strip x all 384 cols, 512 threads. A staged once; B staged
// in LDS in 3 chunks of 128 cols. Register ping-pong prefetch of B chunks
// (measured good round 9): chunk 0 loads before the A barrier, chunk ci+1
// loads before chunk ci's MFMA section -> L2 latency hides under compute,
// barrier critical section is a bare ds_write. z stored bf16.
__launch_bounds__(512)
__global__ void k_gemm(const void* __restrict__ hin, int in_bf16,
                       const float* __restrict__ gs,
                       const bf16* __restrict__ Bt, const float* __restrict__ bias,
                       bf16* __restrict__ y, bf16* __restrict__ z) {
    __shared__ bf16 As[64 * 136];    // 17.4 KB
    __shared__ bf16 Bs[128 * 136];   // 34.8 KB
    int t = threadIdx.x;
    int m0 = blockIdx.x * 64;
    // per-thread BN constants for its 4 fixed columns (sum 8 stats copies)
    int c4 = (t & 31) * 4;
    float mu[4], rs[4];
    for (int c = 0; c < 4; c++) {
        float ssum = 0.f, qsum = 0.f;
        #pragma unroll
        for (int k = 0; k < 8; k++) {
            ssum += gs[k * 256 + c4 + c];
            qsum += gs[k * 256 + 128 + c4 + c];
        }
        float mm = ssum * (1.0f / N_NODES);
        float qq = qsum * (1.0f / N_NODES);
        mu[c] = mm;
        rs[c] = rsqrtf(qq - mm * mm + BN_EPS);
    }
    // prefetch B chunk 0 into regs (latency hides under A staging)
    short8 cur[4], nxt[4];
    #pragma unroll
    for (int rr = 0; rr < 4; rr++) {
        int idx = rr * 512 + t;   // 0..2047
        int row = idx >> 4;       // 0..127
        int kc = idx & 15;        // 16-B chunk within row
        cur[rr] = *(const short8*)(Bt + row * F + kc * 8);
    }
    // stage A (BN applied, -> bf16)
    int r0 = t >> 5;  // 0..15
    for (int it = 0; it < 4; it++) {
        int row = r0 + it * 16;
        int m = m0 + row;
        float f0 = 0.f, f1 = 0.f, f2 = 0.f, f3 = 0.f;
        if (m < N_NODES) {
            if (in_bf16) {
                short4x v = *(const short4x*)((const bf16*)hin + (size_t)m * F + c4);
                f0 = b2f(v.x); f1 = b2f(v.y); f2 = b2f(v.z); f3 = b2f(v.w);
            } else {
                float4 v = *(const float4*)((const float*)hin + (size_t)m * F + c4);
                f0 = v.x; f1 = v.y; f2 = v.z; f3 = v.w;
            }
        }
        bf16 o[4];
        o[0] = __float2bfloat16((f0 - mu[0]) * rs[0] + BETA);
        o[1] = __float2bfloat16((f1 - mu[1]) * rs[1] + BETA);
        o[2] = __float2bfloat16((f2 - mu[2]) * rs[2] + BETA);
        o[3] = __float2bfloat16((f3 - mu[3]) * rs[3] + BETA);
        *(double*)(As + row * 136 + c4) = *(const double*)o;
    }
    __syncthreads();
    int w = t >> 6;
    int lane = t & 63;
    int msub = w & 3;   // m-subtile 0..3
    int nh = w >> 2;    // n-half of chunk 0..1
    int lm = lane & 15;
    int lq = lane >> 4;
    short8 a[4];
    for (int ki = 0; ki < 4; ki++)
        a[ki] = *(const short8*)(As + (msub * 16 + lm) * 136 + ki * 32 + lq * 8);
    int m = m0 + msub * 16 + lm;
    #pragma unroll
    for (int ci = 0; ci < 3; ci++) {
        // write prefetched chunk to Bs (bare ds_write critical section)
        #pragma unroll
        for (int rr = 0; rr < 4; rr++) {
            int idx = rr * 512 + t;
            int row = idx >> 4;
            int kc = idx & 15;
            *(short8*)(Bs + row * 136 + kc * 8) = cur[rr];
        }
        // issue next chunk's loads; latency hides under the MFMA section
        if (ci < 2) {
            const bf16* bsrc = Bt + (size_t)(ci + 1) * 128 * F;
            #pragma unroll
            for (int rr = 0; rr < 4; rr++) {
                int idx = rr * 512 + t;
                int row = idx >> 4;
                int kc = idx & 15;
                nxt[rr] = *(const short8*)(bsrc + row * F + kc * 8);
            }
        }
        __syncthreads();  // Bs ready
        for (int tt = 0; tt < 4; tt++) {
            int nt = nh * 4 + tt;   // n-tile within chunk, 0..7
            short8 b[4];
            for (int ki = 0; ki < 4; ki++)
                b[ki] = *(const short8*)(Bs + (nt * 16 + lm) * 136 + ki * 32 + lq * 8);
            floatx4 acc = {0.f, 0.f, 0.f, 0.f};
            for (int ki = 0; ki < 4; ki++)
                acc = __builtin_amdgcn_mfma_f32_16x16x32_bf16(b[ki], a[ki], acc, 0, 0, 0);
            // D^T: lane holds C[m][n0+reg], n0 = ci*128 + nt*16 + lq*4
            int n0 = ci * 128 + nt * 16 + lq * 4;
            if (m < N_NODES) {
                if (ci < 2) {
                    union { bf16 o[4]; double d; } u;
                    u.o[0] = __float2bfloat16(acc[0]);
                    u.o[1] = __float2bfloat16(acc[1]);
                    u.o[2] = __float2bfloat16(acc[2]);
                    u.o[3] = __float2bfloat16(acc[3]);
                    *(double*)(y + (size_t)m * 256 + n0) = u.d;
                } else {
                    float4 bv = *(const float4*)(bias + (n0 - 256));
                    union { bf16 o[4]; double d; } u;
                    u.o[0] = __float2bfloat16(acc[0] + bv.x);
                    u.o[1] = __float2bfloat16(acc[1] + bv.y);
                    u.o[2] = __float2bfloat16(acc[2] + bv.z);
                    u.o[3] = __float2bfloat16(acc[3] + bv.w);
                    *(double*)(z + (size_t)m * F + (n0 - 256)) = u.d;
                }
            }
        }
        if (ci < 2) {
            __syncthreads();  // Bs readers done before next write
            #pragma unroll
            for (int rr = 0; rr < 4; rr++) cur[rr] = nxt[rr];
        }
    }
}

// ---------------- per-node pull aggregation + relu + residual + fused BN stats ----------------
// One wave per node (50K waves, max TLP). Split-wave by relation. 8-wide
// gather unroll (measured-good; 12-wide regressed — VGPR cliff). Residual
// stream bf16; stats from ROUNDED values, 8-way XCD-replicated.
__launch_bounds__(512)
__global__ void k_aggregate(const bf16* __restrict__ y, const bf16* __restrict__ z,
                            const int* __restrict__ cnt, const int* __restrict__ off,
                            const int* __restrict__ esrc,
                            const bf16* __restrict__ hres, bf16* __restrict__ hb_out,
                            float* __restrict__ out_f32,
                            float* __restrict__ gs_next, int layer) {
    int wid = (blockIdx.x * 512 + threadIdx.x) >> 6;
    int lane = threadIdx.x & 63;
    int n = wid;  // grid is exactly AGGB blocks -> wid < N_NODES always
    int half = lane >> 5;      // 0: rel0, 1: rel1
    int hl = lane & 31;        // lane within half
    int c4 = hl * 4;           // 4 columns per lane
    int2 cc = *(const int2*)(cnt + n * R);
    int o0 = off[n * R];
    int myc = half ? cc.y : cc.x;
    int myo = half ? (o0 + cc.x) : o0;
    float myinv = (myc > 0) ? 1.0f / (float)myc : 0.f;
    const bf16* yb = y + half * 128 + c4;
    float s0 = 0.f, s1 = 0.f, s2 = 0.f, s3 = 0.f;
    for (int i = 0; i < myc; i += 8) {
        int sn[8];
        #pragma unroll
        for (int k = 0; k < 8; k++) {
            int valid = (i + k < myc);
            sn[k] = esrc[valid ? (myo + i + k) : myo];
        }
        short4x p[8];
        #pragma unroll
        for (int k = 0; k < 8; k++)
            p[k] = *(const short4x*)(yb + (size_t)sn[k] * 256);
        #pragma unroll
        for (int k = 0; k < 8; k++) {
            float wk = (i + k < myc) ? myinv : 0.f;
            s0 = fmaf(b2f(p[k].x), wk, s0);
            s1 = fmaf(b2f(p[k].y), wk, s1);
            s2 = fmaf(b2f(p[k].z), wk, s2);
            s3 = fmaf(b2f(p[k].w), wk, s3);
        }
    }
    // combine rel0 + rel1 partners (lane ^ 32)
    float t0 = __shfl_xor(s0, 32, 64);
    float t1 = __shfl_xor(s1, 32, 64);
    float t2 = __shfl_xor(s2, 32, 64);
    float t3 = __shfl_xor(s3, 32, 64);
    __shared__ float ls[8][128], lq[8][128];
    int wv = threadIdx.x >> 6;
    if (half == 0) {
        short4x zb = *(const short4x*)(z + (size_t)n * F + c4);
        float4 hp = {0.f, 0.f, 0.f, 0.f};
        if (layer > 0) {
            short4x hv = *(const short4x*)(hres + (size_t)n * F + c4);
            hp.x = b2f(hv.x); hp.y = b2f(hv.y); hp.z = b2f(hv.z); hp.w = b2f(hv.w);
        }
        float4 o4;
        o4.x = fmaxf(b2f(zb.x) + s0 + t0, 0.f) + hp.x;
        o4.y = fmaxf(b2f(zb.y) + s1 + t1, 0.f) + hp.y;
        o4.z = fmaxf(b2f(zb.z) + s2 + t2, 0.f) + hp.z;
        o4.w = fmaxf(b2f(zb.w) + s3 + t3, 0.f) + hp.w;
        if (out_f32) {
            *(float4*)(out_f32 + (size_t)n * F + c4) = o4;
        } else {
            bf16 ob[4];
            ob[0] = __float2bfloat16(o4.x);
            ob[1] = __float2bfloat16(o4.y);
            ob[2] = __float2bfloat16(o4.z);
            ob[3] = __float2bfloat16(o4.w);
            *(double*)(hb_out + (size_t)n * F + c4) = *(const double*)ob;
            if (gs_next) {
                float r0v = b2f(*(const short*)&ob[0]);
                float r1v = b2f(*(const short*)&ob[1]);
                float r2v = b2f(*(const short*)&ob[2]);
                float r3v = b2f(*(const short*)&ob[3]);
                ls[wv][c4 + 0] = r0v; ls[wv][c4 + 1] = r1v;
                ls[wv][c4 + 2] = r2v; ls[wv][c4 + 3] = r3v;
                lq[wv][c4 + 0] = r0v * r0v; lq[wv][c4 + 1] = r1v * r1v;
                lq[wv][c4 + 2] = r2v * r2v; lq[wv][c4 + 3] = r3v * r3v;
            }
        }
    }
    if (gs_next) {
        __syncthreads();
        int t = threadIdx.x;
        float* gsc = gs_next + (blockIdx.x & 7) * 256;
        if (t < 128) {
            float S = ((ls[0][t] + ls[1][t]) + (ls[2][t] + ls[3][t]))
                    + ((ls[4][t] + ls[5][t]) + (ls[6][t] + ls[7][t]));
            atomicAdd(&gsc[t], S);
        } else if (t < 256) {
            int c = t - 128;
            float Q = ((lq[0][c] + lq[1][c]) + (lq[2][c] + lq[3][c]))
                    + ((lq[4][c] + lq[5][c]) + (lq[6][c] + lq[7][c]));
            atomicAdd(&gsc[128 + c], Q);
        }
    }
}

extern "C" void kernel_launch(void* const* d_in, const int* in_sizes, int n_in,
                              void* d_out, int out_size, void* d_ws, size_t ws_size,
                              hipStream_t stream) {
    const float* x       = (const float*)d_in[0];
    const int*   eidx    = (const int*)d_in[1];
    const int*   etype   = (const int*)d_in[2];
    const float* W0_rel  = (const float*)d_in[3];
    const float* W0_root = (const float*)d_in[4];
    const float* b0      = (const float*)d_in[5];
    const float* Ws_rel  = (const float*)d_in[6];
    const float* Ws_root = (const float*)d_in[7];
    const float* bs      = (const float*)d_in[8];
    const int* src = eidx;
    const int* dst = eidx + N_EDGES;

    char* w = (char*)d_ws;
    bf16*  hb  = (bf16*)w;  w += (size_t)N_NODES * F * 2;     // 12.8 MB residual stream
    bf16*  z   = (bf16*)w;  w += (size_t)N_NODES * F * 2;     // 12.8 MB
    bf16*  y   = (bf16*)w;  w += (size_t)N_NODES * 256 * 2;   // 25.6 MB
    bf16*  Bt  = (bf16*)w;  w += (size_t)NLAYER * NB * F * 2; // 384 KB
    int* cnt   = (int*)w;   w += (size_t)NSEG * 4;            // contiguous zero region:
    int* fill  = (int*)w;   w += (size_t)NSEG * 4;            //   cnt | fill | stats | bcnt
    float* stats = (float*)w; w += (size_t)NLAYER * STATS_STRIDE * 4; // 8 copies/layer
    int* bcnt  = (int*)w;   w += 8 * 4;
    int* off   = (int*)w;   w += (size_t)NSEG * 4;
    int* esrc  = (int*)w;   w += (size_t)N_EDGES * 4;
    int* eseg  = (int*)w;   w += (size_t)PCAP * 8 * 4;        // 2.46 MB bucketed seg
    int* esrcb = (int*)w;   w += (size_t)PCAP * 8 * 4;        // 2.46 MB bucketed src
    int* bsum  = (int*)w;   w += 128 * 4;                     // total ~60 MB

    hipMemsetAsync(cnt, 0,
        (size_t)NSEG * 4 * 2 + (size_t)NLAYER * STATS_STRIDE * 4 + 8 * 4, stream);
    k_wt<<<(NLAYER * NB * F + 255) / 256, 256, 0, stream>>>(W0_rel, W0_root, Ws_rel, Ws_root, Bt);
    k_part<<<PARTB, 256, 0, stream>>>(dst, etype, src, eseg, esrcb, bcnt);
    k_count<<<2048, 256, 0, stream>>>(eseg, bcnt, cnt);
    k_scan1<<<NSCB, 1024, 0, stream>>>(cnt, off, bsum);
    k_scan3<<<NSCB, 1024, 0, stream>>>(off, bsum);
    k_fill<<<2048, 256, 0, stream>>>(eseg, esrcb, bcnt, off, fill, esrc);
    k_bnstats<<<512, 256, 0, stream>>>(x, stats);  // layer-0 stats (copy 0)

    for (int l = 0; l < NLAYER; l++) {
        const float* gsl = stats + (size_t)l * STATS_STRIDE;
        const float* bias = (l == 0) ? b0 : (bs + (size_t)(l - 1) * F);
        const void* hin = (l == 0) ? (const void*)x : (const void*)hb;
        k_gemm<<<(N_NODES + 63) / 64, 512, 0, stream>>>(
            hin, (l > 0) ? 1 : 0, gsl, Bt + (size_t)l * NB * F, bias, y, z);
        k_aggregate<<<AGGB, 512, 0, stream>>>(
            y, z, cnt, off, esrc, hb, hb,
            (l == 3) ? (float*)d_out : nullptr,
            (l < 3) ? (float*)(stats + (size_t)(l + 1) * STATS_STRIDE) : nullptr, l);
    }
}

// Round 12
// 417.492 us; speedup vs baseline: 1.0293x; 1.0293x over previous
//
#include <hip/hip_runtime.h>
#include <hip/hip_bf16.h>

#define N_NODES 50000
#define N_EDGES 600000
#define F 128
#define R 2
#define NLAYER 4
#define NSEG (N_NODES * R)  /* 100000 */
#define SEGP (NSEG / 8)     /* 12500 segments per XCD group */
#define NSCB 98             /* scan blocks: ceil(100000/1024) */
#define NB 384              /* gemm out cols: 256 y + 128 z */
#define STATS_STRIDE 2048   /* 8 copies x 256 floats per layer */
#define AGGB 6250           /* aggregate blocks: 512 thr -> 50000 waves */
#define BN_EPS 1e-5f
#define BETA 1e-4f

typedef __hip_bfloat16 bf16;
typedef __attribute__((ext_vector_type(8))) short short8;  // 8 bf16 (4 VGPRs)
typedef __attribute__((ext_vector_type(4))) short short4x; // 4 bf16 (2 VGPRs)
typedef __attribute__((ext_vector_type(4))) float floatx4; // 4 fp32 acc

__device__ __forceinline__ float b2f(short s) {
    union { unsigned u; float f; } c;
    c.u = ((unsigned)(unsigned short)s) << 16;
    return c.f;
}

// ---------------- weight transpose + f32->bf16: Bt[l][j][d] = W[l][d][j] ----------------
// cols j: [0,128)=W_rel[0], [128,256)=W_rel[1], [256,384)=W_root
__global__ void k_wt(const float* __restrict__ W0_rel, const float* __restrict__ W0_root,
                     const float* __restrict__ Ws_rel, const float* __restrict__ Ws_root,
                     bf16* __restrict__ Bt) {
    int idx = blockIdx.x * 256 + threadIdx.x;
    if (idx >= NLAYER * NB * F) return;
    int l = idx / (NB * F);
    int rem = idx % (NB * F);
    int j = rem / F, d = rem % F;
    float v;
    if (j < 256) {
        int r = j >> 7, c = j & 127;
        v = (l == 0) ? W0_rel[(r * F + d) * F + c]
                     : Ws_rel[((size_t)((l - 1) * R + r) * F + d) * F + c];
    } else {
        int c = j - 256;
        v = (l == 0) ? W0_root[d * F + c]
                     : Ws_root[((size_t)(l - 1) * F + d) * F + c];
    }
    Bt[idx] = __float2bfloat16(v);
}

// ---------------- seg precompute: seg[e] = dst[e]*R + et[e] ----------------
// Halves the read traffic of the 8x ownership rescans in k_count/k_fill.
// NOTE (r11): the one-pass bucket partition alternative REGRESSED (+12us) —
// its scattered cross-XCD bucket writes recreate the round-0 line-bounce.
// Redundant XCD-local reads of L3-hot data beat write-creating passes.
__global__ void k_seg(const int* __restrict__ dst, const int* __restrict__ et,
                      int* __restrict__ seg) {
    int e = blockIdx.x * 256 + threadIdx.x;
    if (e < N_EDGES) seg[e] = dst[e] * R + et[e];
}

// ---------------- segment counts (XCD-partitioned) ----------------
// blocks with blockIdx&7==g own segment range [g*SEGP,(g+1)*SEGP) -> cnt
// lines stay in ONE XCD's L2 (no cross-XCD atomic line bounce).
__global__ void k_count(const int* __restrict__ seg, int* __restrict__ cnt) {
    int g = blockIdx.x & 7;
    int lo = g * SEGP, hi = lo + SEGP;
    for (int e = (blockIdx.x >> 3) * 256 + threadIdx.x; e < N_EDGES; e += 65536) {
        int s = seg[e];
        if (s >= lo && s < hi) atomicAdd(&cnt[s], 1);
    }
}

// ---------------- multi-block exclusive scan of cnt ----------------
__global__ void k_scan1(const int* __restrict__ cnt, int* __restrict__ off,
                        int* __restrict__ bsum) {
    int t = threadIdx.x;
    int g = blockIdx.x * 1024 + t;
    int v = (g < NSEG) ? cnt[g] : 0;
    int lane = t & 63;
    int wv = t >> 6;
    int x = v;
    for (int d = 1; d < 64; d <<= 1) {
        int y = __shfl_up(x, d, 64);
        if (lane >= d) x += y;
    }
    __shared__ int wtot[16];
    if (lane == 63) wtot[wv] = x;
    __syncthreads();
    if (t < 16) {
        int s = wtot[t];
        for (int d = 1; d < 16; d <<= 1) {
            int y = __shfl_up(s, d, 64);
            if (t >= d) s += y;
        }
        wtot[t] = s;
    }
    __syncthreads();
    int wpre = (wv == 0) ? 0 : wtot[wv - 1];
    int incl = x + wpre;
    if (g < NSEG) off[g] = incl - v;  // exclusive within block
    if (t == 1023) bsum[blockIdx.x] = incl;  // raw block total
}

// scan2 merged in: each block's thread 0 sums preceding block totals (L2-hot).
__global__ void k_scan3(int* __restrict__ off, const int* __restrict__ bsum) {
    __shared__ int pre;
    if (threadIdx.x == 0) {
        int p = 0;
        for (int b = 0; b < blockIdx.x; b++) p += bsum[b];
        pre = p;
    }
    __syncthreads();
    int g = blockIdx.x * 1024 + threadIdx.x;
    if (g < NSEG) off[g] += pre;
}

// ---------------- fill segment-sorted src list (XCD-partitioned) ----------------
__global__ void k_fill(const int* __restrict__ src, const int* __restrict__ seg,
                       const int* __restrict__ off,
                       int* __restrict__ fill, int* __restrict__ esrc) {
    int g = blockIdx.x & 7;
    int lo = g * SEGP, hi = lo + SEGP;
    for (int e = (blockIdx.x >> 3) * 256 + threadIdx.x; e < N_EDGES; e += 65536) {
        int s = seg[e];
        if (s >= lo && s < hi) {
            int idx = off[s] + atomicAdd(&fill[s], 1);
            esrc[idx] = src[e];
        }
    }
}

// ---------------- BN column stats for x (layer 0 only) ----------------
// Writes copy 0 of the 8-way stats buffer; copies 1-7 stay zero (memset).
__global__ void k_bnstats(const float* __restrict__ h, float* __restrict__ gs) {
    int c = threadIdx.x & 127;
    int rl = threadIdx.x >> 7;
    float s = 0.f, q = 0.f;
    for (int r = blockIdx.x * 2 + rl; r < N_NODES; r += gridDim.x * 2) {
        float v = h[(size_t)r * F + c];
        s += v; q += v * v;
    }
    __shared__ float ls[256], lq[256];
    ls[threadIdx.x] = s; lq[threadIdx.x] = q;
    __syncthreads();
    if (rl == 0) {
        atomicAdd(&gs[c], ls[c] + ls[c + 128]);
        atomicAdd(&gs[128 + c], lq[c] + lq[c + 128]);
    }
}

// ---------------- fused BN-apply + GEMM: [y|z] = bn(h) @ [Wr0|Wr1|Wroot] ----------------
// Block = 64-row strip x all 384 cols, 512 threads. A staged once; B staged
// in LDS in 3 chunks of 128 cols. Register ping-pong prefetch of B chunks
// (measured good round 9): chunk 0 loads before the A barrier, chunk ci+1
// loads before chunk ci's MFMA section -> L2 latency hides under compute,
// barrier critical section is a bare ds_write. z stored bf16.
__launch_bounds__(512)
__global__ void k_gemm(const void* __restrict__ hin, int in_bf16,
                       const float* __restrict__ gs,
                       const bf16* __restrict__ Bt, const float* __restrict__ bias,
                       bf16* __restrict__ y, bf16* __restrict__ z) {
    __shared__ bf16 As[64 * 136];    // 17.4 KB
    __shared__ bf16 Bs[128 * 136];   // 34.8 KB
    int t = threadIdx.x;
    int m0 = blockIdx.x * 64;
    // per-thread BN constants for its 4 fixed columns (sum 8 stats copies)
    int c4 = (t & 31) * 4;
    float mu[4], rs[4];
    for (int c = 0; c < 4; c++) {
        float ssum = 0.f, qsum = 0.f;
        #pragma unroll
        for (int k = 0; k < 8; k++) {
            ssum += gs[k * 256 + c4 + c];
            qsum += gs[k * 256 + 128 + c4 + c];
        }
        float mm = ssum * (1.0f / N_NODES);
        float qq = qsum * (1.0f / N_NODES);
        mu[c] = mm;
        rs[c] = rsqrtf(qq - mm * mm + BN_EPS);
    }
    // prefetch B chunk 0 into regs (latency hides under A staging)
    short8 cur[4], nxt[4];
    #pragma unroll
    for (int rr = 0; rr < 4; rr++) {
        int idx = rr * 512 + t;   // 0..2047
        int row = idx >> 4;       // 0..127
        int kc = idx & 15;        // 16-B chunk within row
        cur[rr] = *(const short8*)(Bt + row * F + kc * 8);
    }
    // stage A (BN applied, -> bf16)
    int r0 = t >> 5;  // 0..15
    for (int it = 0; it < 4; it++) {
        int row = r0 + it * 16;
        int m = m0 + row;
        float f0 = 0.f, f1 = 0.f, f2 = 0.f, f3 = 0.f;
        if (m < N_NODES) {
            if (in_bf16) {
                short4x v = *(const short4x*)((const bf16*)hin + (size_t)m * F + c4);
                f0 = b2f(v.x); f1 = b2f(v.y); f2 = b2f(v.z); f3 = b2f(v.w);
            } else {
                float4 v = *(const float4*)((const float*)hin + (size_t)m * F + c4);
                f0 = v.x; f1 = v.y; f2 = v.z; f3 = v.w;
            }
        }
        bf16 o[4];
        o[0] = __float2bfloat16((f0 - mu[0]) * rs[0] + BETA);
        o[1] = __float2bfloat16((f1 - mu[1]) * rs[1] + BETA);
        o[2] = __float2bfloat16((f2 - mu[2]) * rs[2] + BETA);
        o[3] = __float2bfloat16((f3 - mu[3]) * rs[3] + BETA);
        *(double*)(As + row * 136 + c4) = *(const double*)o;
    }
    __syncthreads();
    int w = t >> 6;
    int lane = t & 63;
    int msub = w & 3;   // m-subtile 0..3
    int nh = w >> 2;    // n-half of chunk 0..1
    int lm = lane & 15;
    int lq = lane >> 4;
    short8 a[4];
    for (int ki = 0; ki < 4; ki++)
        a[ki] = *(const short8*)(As + (msub * 16 + lm) * 136 + ki * 32 + lq * 8);
    int m = m0 + msub * 16 + lm;
    #pragma unroll
    for (int ci = 0; ci < 3; ci++) {
        // write prefetched chunk to Bs (bare ds_write critical section)
        #pragma unroll
        for (int rr = 0; rr < 4; rr++) {
            int idx = rr * 512 + t;
            int row = idx >> 4;
            int kc = idx & 15;
            *(short8*)(Bs + row * 136 + kc * 8) = cur[rr];
        }
        // issue next chunk's loads; latency hides under the MFMA section
        if (ci < 2) {
            const bf16* bsrc = Bt + (size_t)(ci + 1) * 128 * F;
            #pragma unroll
            for (int rr = 0; rr < 4; rr++) {
                int idx = rr * 512 + t;
                int row = idx >> 4;
                int kc = idx & 15;
                nxt[rr] = *(const short8*)(bsrc + row * F + kc * 8);
            }
        }
        __syncthreads();  // Bs ready
        for (int tt = 0; tt < 4; tt++) {
            int nt = nh * 4 + tt;   // n-tile within chunk, 0..7
            short8 b[4];
            for (int ki = 0; ki < 4; ki++)
                b[ki] = *(const short8*)(Bs + (nt * 16 + lm) * 136 + ki * 32 + lq * 8);
            floatx4 acc = {0.f, 0.f, 0.f, 0.f};
            for (int ki = 0; ki < 4; ki++)
                acc = __builtin_amdgcn_mfma_f32_16x16x32_bf16(b[ki], a[ki], acc, 0, 0, 0);
            // D^T: lane holds C[m][n0+reg], n0 = ci*128 + nt*16 + lq*4
            int n0 = ci * 128 + nt * 16 + lq * 4;
            if (m < N_NODES) {
                if (ci < 2) {
                    union { bf16 o[4]; double d; } u;
                    u.o[0] = __float2bfloat16(acc[0]);
                    u.o[1] = __float2bfloat16(acc[1]);
                    u.o[2] = __float2bfloat16(acc[2]);
                    u.o[3] = __float2bfloat16(acc[3]);
                    *(double*)(y + (size_t)m * 256 + n0) = u.d;
                } else {
                    float4 bv = *(const float4*)(bias + (n0 - 256));
                    union { bf16 o[4]; double d; } u;
                    u.o[0] = __float2bfloat16(acc[0] + bv.x);
                    u.o[1] = __float2bfloat16(acc[1] + bv.y);
                    u.o[2] = __float2bfloat16(acc[2] + bv.z);
                    u.o[3] = __float2bfloat16(acc[3] + bv.w);
                    *(double*)(z + (size_t)m * F + (n0 - 256)) = u.d;
                }
            }
        }
        if (ci < 2) {
            __syncthreads();  // Bs readers done before next write
            #pragma unroll
            for (int rr = 0; rr < 4; rr++) cur[rr] = nxt[rr];
        }
    }
}

// ---------------- per-node pull aggregation + relu + residual + fused BN stats ----------------
// One wave per node (50K waves, max TLP). Split-wave by relation. 8-wide
// gather unroll (measured-good; 12-wide regressed — VGPR cliff). Residual
// stream bf16; stats from ROUNDED values, 8-way XCD-replicated.
__launch_bounds__(512)
__global__ void k_aggregate(const bf16* __restrict__ y, const bf16* __restrict__ z,
                            const int* __restrict__ cnt, const int* __restrict__ off,
                            const int* __restrict__ esrc,
                            const bf16* __restrict__ hres, bf16* __restrict__ hb_out,
                            float* __restrict__ out_f32,
                            float* __restrict__ gs_next, int layer) {
    int wid = (blockIdx.x * 512 + threadIdx.x) >> 6;
    int lane = threadIdx.x & 63;
    int n = wid;  // grid is exactly AGGB blocks -> wid < N_NODES always
    int half = lane >> 5;      // 0: rel0, 1: rel1
    int hl = lane & 31;        // lane within half
    int c4 = hl * 4;           // 4 columns per lane
    int2 cc = *(const int2*)(cnt + n * R);
    int o0 = off[n * R];
    int myc = half ? cc.y : cc.x;
    int myo = half ? (o0 + cc.x) : o0;
    float myinv = (myc > 0) ? 1.0f / (float)myc : 0.f;
    const bf16* yb = y + half * 128 + c4;
    float s0 = 0.f, s1 = 0.f, s2 = 0.f, s3 = 0.f;
    for (int i = 0; i < myc; i += 8) {
        int sn[8];
        #pragma unroll
        for (int k = 0; k < 8; k++) {
            int valid = (i + k < myc);
            sn[k] = esrc[valid ? (myo + i + k) : myo];
        }
        short4x p[8];
        #pragma unroll
        for (int k = 0; k < 8; k++)
            p[k] = *(const short4x*)(yb + (size_t)sn[k] * 256);
        #pragma unroll
        for (int k = 0; k < 8; k++) {
            float wk = (i + k < myc) ? myinv : 0.f;
            s0 = fmaf(b2f(p[k].x), wk, s0);
            s1 = fmaf(b2f(p[k].y), wk, s1);
            s2 = fmaf(b2f(p[k].z), wk, s2);
            s3 = fmaf(b2f(p[k].w), wk, s3);
        }
    }
    // combine rel0 + rel1 partners (lane ^ 32)
    float t0 = __shfl_xor(s0, 32, 64);
    float t1 = __shfl_xor(s1, 32, 64);
    float t2 = __shfl_xor(s2, 32, 64);
    float t3 = __shfl_xor(s3, 32, 64);
    __shared__ float ls[8][128], lq[8][128];
    int wv = threadIdx.x >> 6;
    if (half == 0) {
        short4x zb = *(const short4x*)(z + (size_t)n * F + c4);
        float4 hp = {0.f, 0.f, 0.f, 0.f};
        if (layer > 0) {
            short4x hv = *(const short4x*)(hres + (size_t)n * F + c4);
            hp.x = b2f(hv.x); hp.y = b2f(hv.y); hp.z = b2f(hv.z); hp.w = b2f(hv.w);
        }
        float4 o4;
        o4.x = fmaxf(b2f(zb.x) + s0 + t0, 0.f) + hp.x;
        o4.y = fmaxf(b2f(zb.y) + s1 + t1, 0.f) + hp.y;
        o4.z = fmaxf(b2f(zb.z) + s2 + t2, 0.f) + hp.z;
        o4.w = fmaxf(b2f(zb.w) + s3 + t3, 0.f) + hp.w;
        if (out_f32) {
            *(float4*)(out_f32 + (size_t)n * F + c4) = o4;
        } else {
            bf16 ob[4];
            ob[0] = __float2bfloat16(o4.x);
            ob[1] = __float2bfloat16(o4.y);
            ob[2] = __float2bfloat16(o4.z);
            ob[3] = __float2bfloat16(o4.w);
            *(double*)(hb_out + (size_t)n * F + c4) = *(const double*)ob;
            if (gs_next) {
                float r0v = b2f(*(const short*)&ob[0]);
                float r1v = b2f(*(const short*)&ob[1]);
                float r2v = b2f(*(const short*)&ob[2]);
                float r3v = b2f(*(const short*)&ob[3]);
                ls[wv][c4 + 0] = r0v; ls[wv][c4 + 1] = r1v;
                ls[wv][c4 + 2] = r2v; ls[wv][c4 + 3] = r3v;
                lq[wv][c4 + 0] = r0v * r0v; lq[wv][c4 + 1] = r1v * r1v;
                lq[wv][c4 + 2] = r2v * r2v; lq[wv][c4 + 3] = r3v * r3v;
            }
        }
    }
    if (gs_next) {
        __syncthreads();
        int t = threadIdx.x;
        float* gsc = gs_next + (blockIdx.x & 7) * 256;
        if (t < 128) {
            float S = ((ls[0][t] + ls[1][t]) + (ls[2][t] + ls[3][t]))
                    + ((ls[4][t] + ls[5][t]) + (ls[6][t] + ls[7][t]));
            atomicAdd(&gsc[t], S);
        } else if (t < 256) {
            int c = t - 128;
            float Q = ((lq[0][c] + lq[1][c]) + (lq[2][c] + lq[3][c]))
                    + ((lq[4][c] + lq[5][c]) + (lq[6][c] + lq[7][c]));
            atomicAdd(&gsc[128 + c], Q);
        }
    }
}

extern "C" void kernel_launch(void* const* d_in, const int* in_sizes, int n_in,
                              void* d_out, int out_size, void* d_ws, size_t ws_size,
                              hipStream_t stream) {
    const float* x       = (const float*)d_in[0];
    const int*   eidx    = (const int*)d_in[1];
    const int*   etype   = (const int*)d_in[2];
    const float* W0_rel  = (const float*)d_in[3];
    const float* W0_root = (const float*)d_in[4];
    const float* b0      = (const float*)d_in[5];
    const float* Ws_rel  = (const float*)d_in[6];
    const float* Ws_root = (const float*)d_in[7];
    const float* bs      = (const float*)d_in[8];
    const int* src = eidx;
    const int* dst = eidx + N_EDGES;

    char* w = (char*)d_ws;
    bf16*  hb  = (bf16*)w;  w += (size_t)N_NODES * F * 2;     // 12.8 MB residual stream
    bf16*  z   = (bf16*)w;  w += (size_t)N_NODES * F * 2;     // 12.8 MB
    bf16*  y   = (bf16*)w;  w += (size_t)N_NODES * 256 * 2;   // 25.6 MB
    bf16*  Bt  = (bf16*)w;  w += (size_t)NLAYER * NB * F * 2; // 384 KB
    int* cnt   = (int*)w;   w += (size_t)NSEG * 4;            // contiguous zero region:
    int* fill  = (int*)w;   w += (size_t)NSEG * 4;            //   cnt | fill | stats
    float* stats = (float*)w; w += (size_t)NLAYER * STATS_STRIDE * 4; // 8 copies/layer
    int* off   = (int*)w;   w += (size_t)NSEG * 4;
    int* esrc  = (int*)w;   w += (size_t)N_EDGES * 4;
    int* segb  = (int*)w;   w += (size_t)N_EDGES * 4;
    int* bsum  = (int*)w;   w += 128 * 4;                     // total ~55 MB

    hipMemsetAsync(cnt, 0, (size_t)NSEG * 4 * 2 + (size_t)NLAYER * STATS_STRIDE * 4, stream);
    k_wt<<<(NLAYER * NB * F + 255) / 256, 256, 0, stream>>>(W0_rel, W0_root, Ws_rel, Ws_root, Bt);
    k_seg<<<(N_EDGES + 255) / 256, 256, 0, stream>>>(dst, etype, segb);
    k_count<<<2048, 256, 0, stream>>>(segb, cnt);
    k_scan1<<<NSCB, 1024, 0, stream>>>(cnt, off, bsum);
    k_scan3<<<NSCB, 1024, 0, stream>>>(off, bsum);
    k_fill<<<2048, 256, 0, stream>>>(src, segb, off, fill, esrc);
    k_bnstats<<<512, 256, 0, stream>>>(x, stats);  // layer-0 stats (copy 0)

    for (int l = 0; l < NLAYER; l++) {
        const float* gsl = stats + (size_t)l * STATS_STRIDE;
        const float* bias = (l == 0) ? b0 : (bs + (size_t)(l - 1) * F);
        const void* hin = (l == 0) ? (const void*)x : (const void*)hb;
        k_gemm<<<(N_NODES + 63) / 64, 512, 0, stream>>>(
            hin, (l > 0) ? 1 : 0, gsl, Bt + (size_t)l * NB * F, bias, y, z);
        k_aggregate<<<AGGB, 512, 0, stream>>>(
            y, z, cnt, off, esrc, hb, hb,
            (l == 3) ? (float*)d_out : nullptr,
            (l < 3) ? (float*)(stats + (size_t)(l + 1) * STATS_STRIDE) : nullptr, l);
    }
}